// Round 5
// baseline (12451.054 us; speedup 1.0000x reference)
//
#include <hip/hip_runtime.h>
#include <hip/hip_bf16.h>

// Persistent-weights LSTM for MI355X.  B=32, T=1024, D_IN=512, H=512.
// R5: 32 WGs x 256 threads (was 64) — each WG owns 16 h-cols x 4 gates.
// Halves the number of broadcast consumers (poll/load traffic per record
// line) at the cost of 2x MFMA and 2x weight VGPRs per wave (256 regs).
// Split-phase poll: fast path loads full 8B self-validating records
// {epoch|2xf16}; on miss, spin on 4B epoch hi-words only, then one 4B
// lo-word data pass (safe: records are stored with single 8B atomics, and
// a lo-read after observing the epoch returns the matching data).
// Still: no producer drain, no flags, no release fence — publish is one
// fire-and-forget 8B store per thread. 1 __syncthreads per step.

#define T_STEPS 1024
#define BATCH   32
#define DIN     512
#define H       512
#define NWG     32
#define HC      16
#define XSTRIDE 520        // f16 elems; 1040B row -> 2-way bank alias (free)
#define GSTRIDE 66         // padded f32 row stride of LDS gate tile (64+2)
#define RECS_PER_PARITY 8192   // 16 kk * 512 = full h as {2xf16} records

typedef _Float16 half8  __attribute__((ext_vector_type(8)));
typedef _Float16 half4v __attribute__((ext_vector_type(4)));
typedef float    f32x4  __attribute__((ext_vector_type(4)));
typedef unsigned long long u64;
typedef unsigned int       u32;

#define AT_LD_U64(p)   __hip_atomic_load((const u64*)(p), __ATOMIC_RELAXED, __HIP_MEMORY_SCOPE_AGENT)
#define AT_LD_U32(p)   __hip_atomic_load((const u32*)(p), __ATOMIC_RELAXED, __HIP_MEMORY_SCOPE_AGENT)
#define AT_ST_U64(p,v) __hip_atomic_store((u64*)(p), (v), __ATOMIC_RELAXED, __HIP_MEMORY_SCOPE_AGENT)

__device__ __forceinline__ float sigmoidf_(float x) {
    return 1.0f / (1.0f + __expf(-x));
}
__device__ __forceinline__ float tanhf_(float x) {
    return 1.0f - 2.0f / (1.0f + __expf(2.0f * x));
}

__global__ __launch_bounds__(256, 1) void lstm_persistent(
    const float* __restrict__ x,
    const float* __restrict__ init_states,
    const float* __restrict__ Wi, const float* __restrict__ Ui, const float* __restrict__ bi,
    const float* __restrict__ Wf, const float* __restrict__ Uf, const float* __restrict__ bf,
    const float* __restrict__ Wc, const float* __restrict__ Uc, const float* __restrict__ bc,
    const float* __restrict__ Wo, const float* __restrict__ Uo, const float* __restrict__ bo,
    float* __restrict__ out,
    u64* __restrict__ hrec)    // 2 parities x 8192 records x 8B = 128 KB
{
    __shared__ _Float16 xbuf[2 * BATCH * XSTRIDE];   // ~66.5 KB
    __shared__ float    gbuf[2 * BATCH * GSTRIDE];   // ~16.9 KB

    const int tid  = threadIdx.x;
    const int wg   = blockIdx.x;
    const int lane = tid & 63;
    const int wave = tid >> 6;
    const int mt   = wave & 1;          // M half: batches 0-15 / 16-31
    const int nt   = wave >> 1;         // gate pair: {i,f} / {g,o}
    const int row  = mt * 16 + (lane & 15);
    const int kq   = lane >> 4;
    const int n_local = lane & 15;      // h-col within WG's 16

    // ---- elementwise identity: thread owns (eb, cols 2ej,2ej+1) -----------
    const int eb = tid >> 3;            // batch 0..31
    const int ej = tid & 7;             // col-pair 0..7
    const int ch = wg * HC + 2 * ej;    // global h-col (even)
    // producer record index (parity-less)
    const int widx = (ch >> 5) * 512 + ((ch & 7) >> 1) * 128 + eb * 4 + ((ch >> 3) & 3);

    // ---- publish h0 FIRST (epoch 1, parity 0) -----------------------------
    float c0 = init_states[BATCH * H + eb * H + ch];
    float c1 = init_states[BATCH * H + eb * H + ch + 1];
    {
        _Float16 h0a = (_Float16)init_states[eb * H + ch];
        _Float16 h0b = (_Float16)init_states[eb * H + ch + 1];
        u32 lo = (u32)__builtin_bit_cast(unsigned short, h0a)
               | ((u32)__builtin_bit_cast(unsigned short, h0b) << 16);
        AT_ST_U64(&hrec[widx], ((u64)1u << 32) | (u64)lo);
    }

    // ---- one-time: weight B-fragments into VGPRs (2 gates per wave) -------
    // gate g = nt*2 + tau;  N-tile tau covers 16 h-cols of gate g.
    half8 bx[32], bh[32];               // [tau*16 + kk], 256 VGPRs total
    #pragma unroll
    for (int tau = 0; tau < 2; ++tau) {
        const int g = nt * 2 + tau;
        const float* Wmat = (g == 0) ? Wi : (g == 1) ? Wf : (g == 2) ? Wc : Wo;
        const float* Umat = (g == 0) ? Ui : (g == 1) ? Uf : (g == 2) ? Uc : Uo;
        const int wcol = wg * HC + n_local;
        #pragma unroll
        for (int kk = 0; kk < 16; ++kk) {
            #pragma unroll
            for (int jj = 0; jj < 8; ++jj) {
                int k = kk * 32 + kq * 8 + jj;
                bx[tau * 16 + kk][jj] = (_Float16)Wmat[k * H + wcol];
                bh[tau * 16 + kk][jj] = (_Float16)Umat[k * H + wcol];
            }
        }
    }

    const float bi0 = bi[ch], bi1 = bi[ch + 1];
    const float bf0 = bf[ch], bf1 = bf[ch + 1];
    const float bc0 = bc[ch], bc1 = bc[ch + 1];
    const float bo0 = bo[ch], bo1 = bo[ch + 1];

    // ---- staging / x-MFMA helpers -----------------------------------------
    auto stage = [&](int t, int buf) {
        const int sb = tid >> 3;
        const int so = (tid & 7) * 4;
        const float* xr = x + ((size_t)sb * T_STEPS + t) * DIN;
        _Float16* xb = &xbuf[buf * (BATCH * XSTRIDE)];
        #pragma unroll
        for (int q = 0; q < 16; ++q) {
            int colq = so + q * 32;
            float4 v = *(const float4*)(xr + colq);
            half4v hv = { (_Float16)v.x, (_Float16)v.y,
                          (_Float16)v.z, (_Float16)v.w };
            *(half4v*)&xb[sb * XSTRIDE + colq] = hv;
        }
    };
    f32x4 accx0, accx1;                 // persistent x-half accumulators
    auto xmm = [&](int buf) {
        f32x4 a0 = {0.f, 0.f, 0.f, 0.f};
        f32x4 a1 = {0.f, 0.f, 0.f, 0.f};
        const _Float16* xr2 = &xbuf[buf * (BATCH * XSTRIDE) + row * XSTRIDE + kq * 8];
        #pragma unroll
        for (int kk = 0; kk < 16; ++kk) {
            half8 a = *(const half8*)(xr2 + kk * 32);
            a0 = __builtin_amdgcn_mfma_f32_16x16x32_f16(a, bx[kk],      a0, 0, 0, 0);
            a1 = __builtin_amdgcn_mfma_f32_16x16x32_f16(a, bx[16 + kk], a1, 0, 0, 0);
        }
        accx0 = a0; accx1 = a1;
    };

    // ---- prologue ---------------------------------------------------------
    stage(0, 0);
    stage(1, 1);
    __syncthreads();
    xmm(0);

    const int ridx_base = row * 4 + kq;

    // ---- main recurrence --------------------------------------------------
    for (int t = 0; t < T_STEPS; ++t) {
        const u64* rb = hrec + (size_t)(t & 1) * RECS_PER_PARITY;
        const u32 target = (u32)(t + 1);

        u32 d[64];                      // lo-words (h data) in A-frag order
        // fast path: one full-record pass, grouped to bound live registers
        {
            u32 ok = 1u;
            #pragma unroll
            for (int g = 0; g < 4; ++g) {
                u64 r[16];
                #pragma unroll
                for (int kk = 0; kk < 4; ++kk)
                    #pragma unroll
                    for (int s = 0; s < 4; ++s)
                        r[kk * 4 + s] = AT_LD_U64(&rb[(g * 4 + kk) * 512 + s * 128 + ridx_base]);
                #pragma unroll
                for (int i = 0; i < 16; ++i) {
                    d[g * 16 + i] = (u32)r[i];
                    ok &= ((u32)(r[i] >> 32) == target) ? 1u : 0u;
                }
            }
            if (!__all((int)ok)) {
                // slow path: spin on epoch hi-words only (4B), then lo pass
                unsigned spins = 0;
                for (;;) {
                    u32 ok2 = 1u;
                    #pragma unroll
                    for (int kk = 0; kk < 16; ++kk)
                        #pragma unroll
                        for (int s = 0; s < 4; ++s) {
                            u32 e = AT_LD_U32(((const u32*)&rb[kk * 512 + s * 128 + ridx_base]) + 1);
                            ok2 &= (e == target) ? 1u : 0u;
                        }
                    if (__all((int)ok2)) break;
                    if (++spins > 300000u) break;   // safety valve
                }
                #pragma unroll
                for (int kk = 0; kk < 16; ++kk)
                    #pragma unroll
                    for (int s = 0; s < 4; ++s)
                        d[kk * 4 + s] = AT_LD_U32((const u32*)&rb[kk * 512 + s * 128 + ridx_base]);
            }
        }
        __builtin_amdgcn_fence(__ATOMIC_ACQUIRE, "workgroup");

        // h-half matmul: A from d[], B from registers; 2 N-tiles interleaved
        float* gb = &gbuf[(t & 1) * (BATCH * GSTRIDE)];
        {
            f32x4 h0 = accx0, h1 = accx1;
            #pragma unroll
            for (int kk = 0; kk < 16; ++kk) {
                union { u32 w[4]; half8 h; } A;
                #pragma unroll
                for (int s = 0; s < 4; ++s) A.w[s] = d[kk * 4 + s];
                h0 = __builtin_amdgcn_mfma_f32_16x16x32_f16(A.h, bh[kk],      h0, 0, 0, 0);
                h1 = __builtin_amdgcn_mfma_f32_16x16x32_f16(A.h, bh[16 + kk], h1, 0, 0, 0);
            }
            #pragma unroll
            for (int r = 0; r < 4; ++r) {
                // C/D layout: col = lane&15, row = (lane>>4)*4 + r
                const int orow = mt * 16 + kq * 4 + r;
                gb[orow * GSTRIDE + (nt * 2 + 0) * 16 + n_local] = h0[r];
                gb[orow * GSTRIDE + (nt * 2 + 1) * 16 + n_local] = h1[r];
            }
        }
        __syncthreads();   // the ONLY barrier per step

        // elementwise gates (2 cols/thread) + state update + publish
        float hv0, hv1;
        {
            const float* gbase = gb + eb * GSTRIDE + 2 * ej;
            float pi0 = gbase[0]  + bi0, pi1 = gbase[1]  + bi1;
            float pf0 = gbase[16] + bf0, pf1 = gbase[17] + bf1;
            float pg0 = gbase[32] + bc0, pg1 = gbase[33] + bc1;
            float po0 = gbase[48] + bo0, po1 = gbase[49] + bo1;
            c0 = sigmoidf_(pf0) * c0 + sigmoidf_(pi0) * tanhf_(pg0);
            c1 = sigmoidf_(pf1) * c1 + sigmoidf_(pi1) * tanhf_(pg1);
            hv0 = sigmoidf_(po0) * tanhf_(c0);
            hv1 = sigmoidf_(po1) * tanhf_(c1);

            if (t + 1 < T_STEPS) {
                u32 lo = (u32)__builtin_bit_cast(unsigned short, (_Float16)hv0)
                       | ((u32)__builtin_bit_cast(unsigned short, (_Float16)hv1) << 16);
                AT_ST_U64(&hrec[(size_t)((t + 1) & 1) * RECS_PER_PARITY + widx],
                          ((u64)(u32)(t + 2) << 32) | (u64)lo);
            }
        }

        // ---- off-critical-path tail ---------------------------------------
        {
            float2 ov = { hv0, hv1 };
            *(float2*)&out[((size_t)eb * T_STEPS + t) * H + ch] = ov;
        }
        if (t + 1 < T_STEPS) {
            xmm((t + 1) & 1);                          // staged last iteration
            if (t + 2 < T_STEPS) stage(t + 2, t & 1);  // consumed 2 steps on
        }
    }
}

extern "C" void kernel_launch(void* const* d_in, const int* in_sizes, int n_in,
                              void* d_out, int out_size, void* d_ws, size_t ws_size,
                              hipStream_t stream) {
    const float* x           = (const float*)d_in[0];
    const float* init_states = (const float*)d_in[1];
    const float* Wi = (const float*)d_in[2];
    const float* Ui = (const float*)d_in[3];
    const float* bi = (const float*)d_in[4];
    const float* Wf = (const float*)d_in[5];
    const float* Uf = (const float*)d_in[6];
    const float* bf = (const float*)d_in[7];
    const float* Wc = (const float*)d_in[8];
    const float* Uc = (const float*)d_in[9];
    const float* bc = (const float*)d_in[10];
    const float* Wo = (const float*)d_in[11];
    const float* Uo = (const float*)d_in[12];
    const float* bo = (const float*)d_in[13];
    float* out = (float*)d_out;

    // ws: 2 x 8192 x 8B h-record buffers (128 KB). Records validated by
    // exact-match epochs; 0xAA poison never matches; re-poisoned each launch.
    u64* hrec = (u64*)d_ws;

    lstm_persistent<<<dim3(NWG), dim3(256), 0, stream>>>(
        x, init_states, Wi, Ui, bi, Wf, Uf, bf, Wc, Uc, bc, Wo, Uo, bo,
        out, hrec);
}